// Round 9
// baseline (58.189 us; speedup 1.0000x reference)
//
#include <hip/hip_runtime.h>

// GrCNetConvOnly: out[b] = sum_{c,d} relu(wa[c]*h[b,d]+wb[c]*r[b,d]+wc[c]*t[b,d]+cb[c]) * fcw[c*D+d] + fcb
// B=16384, D=400, C=50.
// R8 (45.7us) was exposed-latency-bound: 84 dword gathers/wave in 7 short slots (~520cy
// compute vs ~900cy HBM latency), all waves in phase. R9: blocked d-mapping (lane holds
// d=4l..4l+3) -> 24 dwordx4 gathers in 2 slots; slot-A latency hides under fc staging,
// slot-B under slot-A's ~2000cy compute. Packing along d: fc = one ds_read_b64 per c
// (2 pairs), conv = one ds_read_b128 per c, all compile-time offsets. Slot B (d>=256)
// has 36 active lanes, exec-masked via if(lane<36). 8 f32 dot2 accumulator chains.

typedef _Float16 h2 __attribute__((ext_vector_type(2)));
typedef _Float16 h4 __attribute__((ext_vector_type(4)));
typedef _Float16 h8 __attribute__((ext_vector_type(8)));

constexpr int D = 400;
constexpr int C = 50;

static __device__ __forceinline__ float dot2acc(h2 a, h2 b, float c) {
#if __has_builtin(__builtin_amdgcn_fdot2)
    return __builtin_amdgcn_fdot2(a, b, c, false);
#else
    h2 p = a * b; return c + (float)p[0] + (float)p[1];
#endif
}
static __device__ __forceinline__ h2 mk2(float x, float y) {
    h2 r; r[0] = (_Float16)x; r[1] = (_Float16)y; return r;
}

__global__ __attribute__((amdgpu_flat_work_group_size(512, 512), amdgpu_waves_per_eu(2, 4)))
void grcnet_pk16e(
    const float* __restrict__ entity_emb,
    const float* __restrict__ relation_emb,
    const float* __restrict__ conv_w,       // (C,1,1,3)
    const float* __restrict__ conv_b,       // (C)
    const float* __restrict__ fc_w,         // (C*D) c-major
    const float* __restrict__ fc_b,         // (1)
    const int*   __restrict__ batch_inputs, // (B,3)
    float* __restrict__ out,                // (B)
    int nB)
{
    __shared__ __align__(16) h2 fc_lds[C][200];   // 40000 B; [c][d-pair]
    __shared__ __align__(16) h2 conv_lds[C][4];   // 800 B; [c] = wa2,wb2,wc2,cb2
    __shared__ float partials[2][4][4];

    const int tid  = threadIdx.x;
    const int lane = tid & 63;
    const int wv   = tid >> 6;              // 0..7
    const int grp  = wv >> 1;               // b-group 0..3
    const int hc   = wv & 1;                // c-half 0..1
    const int b0   = blockIdx.x * 16;
    if (b0 >= nB) return;

    // ---- row pointers (wave-uniform -> SGPR) ----
    const int bbase = __builtin_amdgcn_readfirstlane(b0 + 4 * grp);
    const int* bi = batch_inputs + 3 * bbase;
    const float* q0h = entity_emb   + (size_t)bi[0]  * D;
    const float* q0r = relation_emb + (size_t)bi[1]  * D;
    const float* q0t = entity_emb   + (size_t)bi[2]  * D;
    const float* q1h = entity_emb   + (size_t)bi[3]  * D;
    const float* q1r = relation_emb + (size_t)bi[4]  * D;
    const float* q1t = entity_emb   + (size_t)bi[5]  * D;
    const float* q2h = entity_emb   + (size_t)bi[6]  * D;
    const float* q2r = relation_emb + (size_t)bi[7]  * D;
    const float* q2t = entity_emb   + (size_t)bi[8]  * D;
    const float* q3h = entity_emb   + (size_t)bi[9]  * D;
    const float* q3r = relation_emb + (size_t)bi[10] * D;
    const float* q3t = entity_emb   + (size_t)bi[11] * D;

    #define ROWS(X) X(0h) X(0r) X(0t) X(1h) X(1r) X(1t) X(2h) X(2r) X(2t) X(3h) X(3r) X(3t)

    // ---- issue slot-A gathers NOW; latency hides under fc staging below ----
    #define LOADA(n) const float4 vA##n = *(const float4*)(q##n + 4 * lane);
    ROWS(LOADA)
    #undef LOADA

    // ---- stage fc_w -> fc_lds (h2 [c][pair]), conv -> conv_lds ----
    for (int k = tid; k < C * 100; k += 512) {
        const int c = k / 100;
        const int q = k - c * 100;
        const float4 v = *(const float4*)(fc_w + c * D + 4 * q);
        h4 g;
        g[0] = (_Float16)v.x; g[1] = (_Float16)v.y;
        g[2] = (_Float16)v.z; g[3] = (_Float16)v.w;
        *(h4*)&fc_lds[c][2 * q] = g;
    }
    if (tid < C) {
        const float a = conv_w[3*tid+0], b = conv_w[3*tid+1];
        const float c = conv_w[3*tid+2], e = conv_b[tid];
        h2 t;
        t[0] = (_Float16)a; t[1] = (_Float16)a; conv_lds[tid][0] = t;
        t[0] = (_Float16)b; t[1] = (_Float16)b; conv_lds[tid][1] = t;
        t[0] = (_Float16)c; t[1] = (_Float16)c; conv_lds[tid][2] = t;
        t[0] = (_Float16)e; t[1] = (_Float16)e; conv_lds[tid][3] = t;
    }
    __syncthreads();

    // ---- convert slot A to h2 d-pairs (24 regs) ----
    #define CVT(S, n) h2 S##n##p0 = mk2(v##S##n.x, v##S##n.y); \
                      h2 S##n##p1 = mk2(v##S##n.z, v##S##n.w);
    #define CVTA(n) CVT(A, n)
    ROWS(CVTA)
    #undef CVTA

    // ---- issue slot-B gathers (d = 256+4l, lanes<36); hide under COMPUTE(A) ----
    const int idxB = (lane < 36) ? (256 + 4 * lane) : 0;
    #define LOADB(n) const float4 vB##n = *(const float4*)(q##n + idxB);
    ROWS(LOADB)
    #undef LOADB

    float acc0p0 = 0.f, acc0p1 = 0.f, acc1p0 = 0.f, acc1p1 = 0.f;
    float acc2p0 = 0.f, acc2p1 = 0.f, acc3p0 = 0.f, acc3p1 = 0.f;
    const h2 zero2 = (h2)(_Float16)0;
    const int c0 = hc * 25;

    #define CSTEP(S, b)                                                   \
        s = S##b##hp0*wa + (S##b##rp0*wb + (S##b##tp0*wc + cb));          \
        s = __builtin_elementwise_max(s, zero2);                          \
        acc##b##p0 = dot2acc(s, f0, acc##b##p0);                          \
        s = S##b##hp1*wa + (S##b##rp1*wb + (S##b##tp1*wc + cb));          \
        s = __builtin_elementwise_max(s, zero2);                          \
        acc##b##p1 = dot2acc(s, f1, acc##b##p1);

    #define COMPUTE(S, FCB)                                               \
    _Pragma("unroll")                                                     \
    for (int j = 0; j < 25; ++j) {                                        \
        const h8 cv = *(const h8*)&conv_lds[c0 + j][0];                   \
        const h2 wa = __builtin_shufflevector(cv, cv, 0, 1);              \
        const h2 wb = __builtin_shufflevector(cv, cv, 2, 3);              \
        const h2 wc = __builtin_shufflevector(cv, cv, 4, 5);              \
        const h2 cb = __builtin_shufflevector(cv, cv, 6, 7);              \
        const h4 fq = *(const h4*)((FCB) + j * 800);                      \
        const h2 f0 = __builtin_shufflevector(fq, fq, 0, 1);              \
        const h2 f1 = __builtin_shufflevector(fq, fq, 2, 3);              \
        h2 s;                                                             \
        CSTEP(S, 0) CSTEP(S, 1) CSTEP(S, 2) CSTEP(S, 3)                   \
    }

    // slot A: d = 4l..4l+3 (pairs 2l, 2l+1), all 64 lanes
    const char* fcA = (const char*)fc_lds + 20000 * hc + 8 * lane;
    COMPUTE(A, fcA)

    // slot B: d = 256+4l (pairs 128+2l, 129+2l), lanes < 36
    if (lane < 36) {
        #define CVTB(n) CVT(B, n)
        ROWS(CVTB)
        #undef CVTB
        const char* fcB = (const char*)fc_lds + 20000 * hc + 512 + 8 * lane;
        COMPUTE(B, fcB)
    }
    #undef COMPUTE
    #undef CSTEP
    #undef CVT
    #undef ROWS

    // ---- reduce ----
    float s0 = acc0p0 + acc0p1, s1 = acc1p0 + acc1p1;
    float s2 = acc2p0 + acc2p1, s3 = acc3p0 + acc3p1;
    #pragma unroll
    for (int off = 32; off > 0; off >>= 1) {
        s0 += __shfl_xor(s0, off);
        s1 += __shfl_xor(s1, off);
        s2 += __shfl_xor(s2, off);
        s3 += __shfl_xor(s3, off);
    }
    if (lane == 0) {
        partials[hc][grp][0] = s0; partials[hc][grp][1] = s1;
        partials[hc][grp][2] = s2; partials[hc][grp][3] = s3;
    }
    __syncthreads();

    if (tid < 16) {
        const int g = tid >> 2, j = tid & 3;
        out[b0 + 4*g + j] = partials[0][g][j] + partials[1][g][j] + fc_b[0];
    }
}

extern "C" void kernel_launch(void* const* d_in, const int* in_sizes, int n_in,
                              void* d_out, int out_size, void* d_ws, size_t ws_size,
                              hipStream_t stream) {
    const float* entity_emb   = (const float*)d_in[0];
    const float* relation_emb = (const float*)d_in[1];
    const float* conv_w       = (const float*)d_in[2];
    const float* conv_b       = (const float*)d_in[3];
    const float* fc_w         = (const float*)d_in[4];
    const float* fc_b         = (const float*)d_in[5];
    const int*   batch_inputs = (const int*)d_in[6];
    float* out = (float*)d_out;

    const int nB = in_sizes[6] / 3;          // 16384
    const int blocks = (nB + 15) / 16;       // 1024
    grcnet_pk16e<<<blocks, 512, 0, stream>>>(
        entity_emb, relation_emb, conv_w, conv_b, fc_w, fc_b, batch_inputs, out, nB);
}

// Round 10
// 47.382 us; speedup vs baseline: 1.2281x; 1.2281x over previous
//
#include <hip/hip_runtime.h>

// GrCNetConvOnly: out[b] = sum_{c,d} relu(wa[c]*h[b,d]+wb[c]*r[b,d]+wc[c]*t[b,d]+cb[c]) * fcw[c*D+d] + fcb
// B=16384, D=400, C=50.
// R8 (45.7us) = 2-deep pipeline: each slot's 12 HBM gathers (~900cy, L3 evicted by harness
// poison fills) covered by only ~520cy of compute -> ~380cy stall x7 slots.
// R10: 3-deep rotating pipeline (A/B/C): every load issued TWO compute phases (~1040cy)
// before use; slots 0+1 issued before fc staging so their latency hides under the
// prologue. Rest identical to R8 (pack along c, cp-split across wave pairs, fc ds_read
// with compile-time offsets, conv hoisted to regs, fdot2 f32 accumulation).

typedef _Float16 h2 __attribute__((ext_vector_type(2)));
typedef _Float16 h8 __attribute__((ext_vector_type(8)));

constexpr int D    = 400;
constexpr int CP   = 25;     // channel pairs
constexpr int DPAD = 404;    // 4 zeroed pad entries: inactive lanes read f2 = 0

static __device__ __forceinline__ float dot2acc(h2 a, h2 b, float c) {
#if __has_builtin(__builtin_amdgcn_fdot2)
    return __builtin_amdgcn_fdot2(a, b, c, false);
#else
    h2 p = a * b; return c + (float)p[0] + (float)p[1];
#endif
}
static __device__ __forceinline__ h2 dup(float v) {
    _Float16 x = (_Float16)v; h2 r; r[0] = x; r[1] = x; return r;
}

__global__ __attribute__((amdgpu_flat_work_group_size(512, 512), amdgpu_waves_per_eu(2, 4)))
void grcnet_pk16f(
    const float* __restrict__ entity_emb,
    const float* __restrict__ relation_emb,
    const float* __restrict__ conv_w,       // (C,1,1,3)
    const float* __restrict__ conv_b,       // (C)
    const float* __restrict__ fc_w,         // (C*D) c-major
    const float* __restrict__ fc_b,         // (1)
    const int*   __restrict__ batch_inputs, // (B,3)
    float* __restrict__ out,                // (B)
    int nB)
{
    __shared__ h2    fc_lds[CP][DPAD];      // 40400 B; elem = {fcw[2cp,d], fcw[2cp+1,d]}
    __shared__ h2    conv_lds[CP][4];       // [cp] = wa2, wb2, wc2, cb2
    __shared__ float partials[2][4][4];

    const int tid  = threadIdx.x;
    const int lane = tid & 63;
    const int wv   = tid >> 6;              // 0..7
    const int grp  = wv >> 1;               // b-group 0..3
    const int hc   = wv & 1;                // cp-half 0..1
    const int b0   = blockIdx.x * 16;
    if (b0 >= nB) return;

    // ---- this wave's 4 batch elements; base pointers pre-offset by lane ----
    const int bbase = __builtin_amdgcn_readfirstlane(b0 + 4 * grp);
    const int* bi = batch_inputs + 3 * bbase;
    const float* p0h = entity_emb   + (size_t)bi[0]  * D + lane;
    const float* p0r = relation_emb + (size_t)bi[1]  * D + lane;
    const float* p0t = entity_emb   + (size_t)bi[2]  * D + lane;
    const float* p1h = entity_emb   + (size_t)bi[3]  * D + lane;
    const float* p1r = relation_emb + (size_t)bi[4]  * D + lane;
    const float* p1t = entity_emb   + (size_t)bi[5]  * D + lane;
    const float* p2h = entity_emb   + (size_t)bi[6]  * D + lane;
    const float* p2r = relation_emb + (size_t)bi[7]  * D + lane;
    const float* p2t = entity_emb   + (size_t)bi[8]  * D + lane;
    const float* p3h = entity_emb   + (size_t)bi[9]  * D + lane;
    const float* p3r = relation_emb + (size_t)bi[10] * D + lane;
    const float* p3t = entity_emb   + (size_t)bi[11] * D + lane;

    // slot 6 (d = lane+384): clamp inactive lanes to row start; fc reads pad row (=0)
    const int  d6  = lane + 384;
    const bool a6  = (d6 < D);
    const int  i6  = a6 ? 384 : -lane;       // p[i6] == row[dc6]
    const h2*  fcb  = (const h2*)fc_lds + lane;          // slots 0..5 fc base
    const h2*  fcb6 = (const h2*)fc_lds + (a6 ? d6 : D); // slot 6 fc base

    #define LOADI(S, IDX)                                                         \
        f##S##_0h = p0h[IDX]; f##S##_0r = p0r[IDX]; f##S##_0t = p0t[IDX];         \
        f##S##_1h = p1h[IDX]; f##S##_1r = p1r[IDX]; f##S##_1t = p1t[IDX];         \
        f##S##_2h = p2h[IDX]; f##S##_2r = p2r[IDX]; f##S##_2t = p2t[IDX];         \
        f##S##_3h = p3h[IDX]; f##S##_3r = p3r[IDX]; f##S##_3t = p3t[IDX];

    // 3 rotating slots of 12 gather values each
    float fA_0h, fA_0r, fA_0t, fA_1h, fA_1r, fA_1t;
    float fA_2h, fA_2r, fA_2t, fA_3h, fA_3r, fA_3t;
    float fB_0h, fB_0r, fB_0t, fB_1h, fB_1r, fB_1t;
    float fB_2h, fB_2r, fB_2t, fB_3h, fB_3r, fB_3t;
    float fC_0h, fC_0r, fC_0t, fC_1h, fC_1r, fC_1t;
    float fC_2h, fC_2r, fC_2t, fC_3h, fC_3r, fC_3t;

    // ---- issue slots 0,1 NOW: latency hides under fc staging + barrier ----
    LOADI(A, 0)
    LOADI(B, 64)

    // ---- stage fc_w: float4 x2 -> one b128 ds_write ----
    for (int k = tid; k < CP * 100; k += 512) {
        const int cp = k / 100;
        const int dq = k - cp * 100;
        const float4 A  = *(const float4*)(fc_w + (2*cp)     * D + 4*dq);
        const float4 Bv = *(const float4*)(fc_w + (2*cp + 1) * D + 4*dq);
        h8 g;
        g[0]=(_Float16)A.x; g[1]=(_Float16)Bv.x;
        g[2]=(_Float16)A.y; g[3]=(_Float16)Bv.y;
        g[4]=(_Float16)A.z; g[5]=(_Float16)Bv.z;
        g[6]=(_Float16)A.w; g[7]=(_Float16)Bv.w;
        *(h8*)&fc_lds[cp][4*dq] = g;
    }
    if (tid < CP * 4) {                      // zero pad d=400..403
        h2 z; z[0] = (_Float16)0; z[1] = (_Float16)0;
        fc_lds[tid >> 2][D + (tid & 3)] = z;
    }
    if (tid < CP) {                          // conv params, pair-packed
        const int c0 = 2 * tid;
        h2 wa, wb, wc, cb;
        wa[0]=(_Float16)conv_w[3*c0+0]; wa[1]=(_Float16)conv_w[3*c0+3];
        wb[0]=(_Float16)conv_w[3*c0+1]; wb[1]=(_Float16)conv_w[3*c0+4];
        wc[0]=(_Float16)conv_w[3*c0+2]; wc[1]=(_Float16)conv_w[3*c0+5];
        cb[0]=(_Float16)conv_b[c0];     cb[1]=(_Float16)conv_b[c0+1];
        conv_lds[tid][0]=wa; conv_lds[tid][1]=wb;
        conv_lds[tid][2]=wc; conv_lds[tid][3]=cb;
    }
    __syncthreads();

    float acc0 = 0.f, acc1 = 0.f, acc2 = 0.f, acc3 = 0.f;
    const h2 zero2 = (h2)(_Float16)0;

    #define COMPUTE(S, FB, FIDX0)                                                 \
    {                                                                             \
        const h2 H0 = dup(f##S##_0h), R0 = dup(f##S##_0r), T0 = dup(f##S##_0t);   \
        const h2 H1 = dup(f##S##_1h), R1 = dup(f##S##_1r), T1 = dup(f##S##_1t);   \
        const h2 H2 = dup(f##S##_2h), R2 = dup(f##S##_2r), T2 = dup(f##S##_2t);   \
        const h2 H3 = dup(f##S##_3h), R3 = dup(f##S##_3r), T3 = dup(f##S##_3t);   \
        _Pragma("unroll")                                                         \
        for (int j = 0; j < NC; ++j) {                                            \
            const h2 f2 = (FB)[(FIDX0) + (C0 + j) * DPAD];  /* imm offset */      \
            h2 s0 = H0*cwa[j] + (R0*cwb[j] + (T0*cwc[j] + ccb[j]));               \
            h2 s1 = H1*cwa[j] + (R1*cwb[j] + (T1*cwc[j] + ccb[j]));               \
            h2 s2 = H2*cwa[j] + (R2*cwb[j] + (T2*cwc[j] + ccb[j]));               \
            h2 s3 = H3*cwa[j] + (R3*cwb[j] + (T3*cwc[j] + ccb[j]));               \
            s0 = __builtin_elementwise_max(s0, zero2);                            \
            s1 = __builtin_elementwise_max(s1, zero2);                            \
            s2 = __builtin_elementwise_max(s2, zero2);                            \
            s3 = __builtin_elementwise_max(s3, zero2);                            \
            acc0 = dot2acc(s0, f2, acc0);                                         \
            acc1 = dot2acc(s1, f2, acc1);                                         \
            acc2 = dot2acc(s2, f2, acc2);                                         \
            acc3 = dot2acc(s3, f2, acc3);                                         \
        }                                                                         \
    }

    // 3-deep rotation: each LOADI is 2 COMPUTE phases (~1040cy) ahead of its use.
    #define BODY(C0_, NC_)                                                        \
    {                                                                             \
        constexpr int C0 = (C0_), NC = (NC_);                                     \
        h2 cwa[NC], cwb[NC], cwc[NC], ccb[NC];                                    \
        _Pragma("unroll")                                                         \
        for (int j = 0; j < NC; ++j) {                                            \
            cwa[j] = conv_lds[C0+j][0]; cwb[j] = conv_lds[C0+j][1];               \
            cwc[j] = conv_lds[C0+j][2]; ccb[j] = conv_lds[C0+j][3];               \
        }                                                                         \
        LOADI(C, 128)  COMPUTE(A, fcb, 0*64)                                      \
        LOADI(A, 192)  COMPUTE(B, fcb, 1*64)                                      \
        LOADI(B, 256)  COMPUTE(C, fcb, 2*64)                                      \
        LOADI(C, 320)  COMPUTE(A, fcb, 3*64)                                      \
        LOADI(A, i6)   COMPUTE(B, fcb, 4*64)                                      \
                       COMPUTE(C, fcb, 5*64)                                      \
                       COMPUTE(A, fcb6, 0)                                        \
    }

    if (hc == 0) { BODY(0, 13) } else { BODY(13, 12) }
    #undef BODY
    #undef COMPUTE
    #undef LOADI

    // ---- wave-wide sum, cross-wave via LDS ----
    #pragma unroll
    for (int off = 32; off > 0; off >>= 1) {
        acc0 += __shfl_xor(acc0, off);
        acc1 += __shfl_xor(acc1, off);
        acc2 += __shfl_xor(acc2, off);
        acc3 += __shfl_xor(acc3, off);
    }
    if (lane == 0) {
        partials[hc][grp][0] = acc0; partials[hc][grp][1] = acc1;
        partials[hc][grp][2] = acc2; partials[hc][grp][3] = acc3;
    }
    __syncthreads();

    if (tid < 16) {
        const int g = tid >> 2, j = tid & 3;
        out[b0 + 4*g + j] = partials[0][g][j] + partials[1][g][j] + fc_b[0];
    }
}

extern "C" void kernel_launch(void* const* d_in, const int* in_sizes, int n_in,
                              void* d_out, int out_size, void* d_ws, size_t ws_size,
                              hipStream_t stream) {
    const float* entity_emb   = (const float*)d_in[0];
    const float* relation_emb = (const float*)d_in[1];
    const float* conv_w       = (const float*)d_in[2];
    const float* conv_b       = (const float*)d_in[3];
    const float* fc_w         = (const float*)d_in[4];
    const float* fc_b         = (const float*)d_in[5];
    const int*   batch_inputs = (const int*)d_in[6];
    float* out = (float*)d_out;

    const int nB = in_sizes[6] / 3;          // 16384
    const int blocks = (nB + 15) / 16;       // 1024
    grcnet_pk16f<<<blocks, 512, 0, stream>>>(
        entity_emb, relation_emb, conv_w, conv_b, fc_w, fc_b, batch_inputs, out, nB);
}

// Round 11
// 44.866 us; speedup vs baseline: 1.2969x; 1.0561x over previous
//
#include <hip/hip_runtime.h>

// GrCNetConvOnly: out[b] = sum_{c,d} relu(wa[c]*h[b,d]+wb[c]*r[b,d]+wc[c]*t[b,d]+cb[c]) * fcw[c*D+d] + fcb
// B=16384, D=400, C=50.
// R8/R10 plateau at ~46us = 3.2x the 14.3us VALU issue floor; pipeline depth + occupancy
// levers all flat. Remaining structural suspects attacked here:
//  1) I-CACHE: R8 emitted TWO ~2000-inst BODY paths (hc=0/1) ~ 32KB ~= L1I size, with
//     wave pairs alternating paths -> unified single BODY, runtime C0=13*hc, hc=1 runs a
//     13th dummy cp whose fc row (row 25) is zeroed in LDS => contributes exactly 0.
//     g-loop kept rolled (unroll 1) so the body is emitted ONCE (~16KB).
//  2) ROUNDS: 1024 blocks = 2 sequential rounds/CU, each re-staging fc. Now 512 blocks
//     x 32 b's = exactly 2 resident blocks/CU, one round, staging amortized 2x.
// Kept from R8 (proven): 2-deep A/B pipeline, pack-along-c pk16 + fdot2 f32 accum,
// imm-offset fc ds_reads (conflict-free), conv hoisted to 52 regs, waves_per_eu(2,4).

typedef _Float16 h2 __attribute__((ext_vector_type(2)));
typedef _Float16 h8 __attribute__((ext_vector_type(8)));

constexpr int D    = 400;
constexpr int CP   = 25;     // real channel pairs
constexpr int DPAD = 404;    // 4 zeroed pad entries per row: inactive lanes read 0

static __device__ __forceinline__ float dot2acc(h2 a, h2 b, float c) {
#if __has_builtin(__builtin_amdgcn_fdot2)
    return __builtin_amdgcn_fdot2(a, b, c, false);
#else
    h2 p = a * b; return c + (float)p[0] + (float)p[1];
#endif
}
static __device__ __forceinline__ h2 dup(float v) {
    _Float16 x = (_Float16)v; h2 r; r[0] = x; r[1] = x; return r;
}

__global__ __attribute__((amdgpu_flat_work_group_size(512, 512), amdgpu_waves_per_eu(2, 4)))
void grcnet_pk16g(
    const float* __restrict__ entity_emb,
    const float* __restrict__ relation_emb,
    const float* __restrict__ conv_w,       // (C,1,1,3)
    const float* __restrict__ conv_b,       // (C)
    const float* __restrict__ fc_w,         // (C*D) c-major
    const float* __restrict__ fc_b,         // (1)
    const int*   __restrict__ batch_inputs, // (B,3)
    float* __restrict__ out,                // (B)
    int nB)
{
    __shared__ h2    fc_lds[CP + 1][DPAD];  // 42016 B; row 25 = zeros (dummy cp)
    __shared__ h2    conv_lds[CP + 1][4];   // row 25 = copy of row 24 (harmless)
    __shared__ float partials[2][2][4][4];  // [g][hc][grp][b]

    const int tid  = threadIdx.x;
    const int lane = tid & 63;
    const int wv   = tid >> 6;              // 0..7
    const int grp  = wv >> 1;               // b-group 0..3
    const int hc   = wv & 1;                // c-half 0..1
    const int bq   = blockIdx.x * 32;       // 32 b per block
    if (bq >= nB) return;

    // mutable row pointers (reset per g)
    const float *p0h, *p0r, *p0t, *p1h, *p1r, *p1t;
    const float *p2h, *p2r, *p2t, *p3h, *p3r, *p3t;

    #define SETPTRS(B0)                                                           \
    {                                                                             \
        const int bbase = __builtin_amdgcn_readfirstlane((B0) + 4 * grp);         \
        const int* bi = batch_inputs + 3 * bbase;                                 \
        p0h = entity_emb   + (size_t)bi[0]  * D + lane;                           \
        p0r = relation_emb + (size_t)bi[1]  * D + lane;                           \
        p0t = entity_emb   + (size_t)bi[2]  * D + lane;                           \
        p1h = entity_emb   + (size_t)bi[3]  * D + lane;                           \
        p1r = relation_emb + (size_t)bi[4]  * D + lane;                           \
        p1t = entity_emb   + (size_t)bi[5]  * D + lane;                           \
        p2h = entity_emb   + (size_t)bi[6]  * D + lane;                           \
        p2r = relation_emb + (size_t)bi[7]  * D + lane;                           \
        p2t = entity_emb   + (size_t)bi[8]  * D + lane;                           \
        p3h = entity_emb   + (size_t)bi[9]  * D + lane;                           \
        p3r = relation_emb + (size_t)bi[10] * D + lane;                           \
        p3t = entity_emb   + (size_t)bi[11] * D + lane;                           \
    }

    #define LOADI(S, IDX)                                                         \
        f##S##_0h = p0h[IDX]; f##S##_0r = p0r[IDX]; f##S##_0t = p0t[IDX];         \
        f##S##_1h = p1h[IDX]; f##S##_1r = p1r[IDX]; f##S##_1t = p1t[IDX];         \
        f##S##_2h = p2h[IDX]; f##S##_2r = p2r[IDX]; f##S##_2t = p2t[IDX];         \
        f##S##_3h = p3h[IDX]; f##S##_3r = p3r[IDX]; f##S##_3t = p3t[IDX];

    float fA_0h, fA_0r, fA_0t, fA_1h, fA_1r, fA_1t;
    float fA_2h, fA_2r, fA_2t, fA_3h, fA_3r, fA_3t;
    float fB_0h, fB_0r, fB_0t, fB_1h, fB_1r, fB_1t;
    float fB_2h, fB_2r, fB_2t, fB_3h, fB_3r, fB_3t;

    // ---- issue g=0 slots 0,1 NOW: latency hides under fc staging + barrier ----
    SETPTRS(bq)
    LOADI(A, 0)
    LOADI(B, 64)

    // ---- stage fc_w: float4 x2 -> one b128 ds_write ----
    for (int k = tid; k < CP * 100; k += 512) {
        const int cp = k / 100;
        const int dq = k - cp * 100;
        const float4 A  = *(const float4*)(fc_w + (2*cp)     * D + 4*dq);
        const float4 Bv = *(const float4*)(fc_w + (2*cp + 1) * D + 4*dq);
        h8 g;
        g[0]=(_Float16)A.x; g[1]=(_Float16)Bv.x;
        g[2]=(_Float16)A.y; g[3]=(_Float16)Bv.y;
        g[4]=(_Float16)A.z; g[5]=(_Float16)Bv.z;
        g[6]=(_Float16)A.w; g[7]=(_Float16)Bv.w;
        *(h8*)&fc_lds[cp][4*dq] = g;
    }
    {
        h2 z; z[0] = (_Float16)0; z[1] = (_Float16)0;
        if (tid < CP * 4) fc_lds[tid >> 2][D + (tid & 3)] = z;   // pad d=400..403
        if (tid >= 64 && tid < 64 + DPAD) fc_lds[CP][tid - 64] = z; // dummy row 25 = 0
    }
    if (tid < CP + 1) {                      // conv params; row 25 mirrors row 24
        const int src = (tid == CP) ? (CP - 1) : tid;
        const int c0 = 2 * src;
        h2 wa, wb, wc, cb;
        wa[0]=(_Float16)conv_w[3*c0+0]; wa[1]=(_Float16)conv_w[3*c0+3];
        wb[0]=(_Float16)conv_w[3*c0+1]; wb[1]=(_Float16)conv_w[3*c0+4];
        wc[0]=(_Float16)conv_w[3*c0+2]; wc[1]=(_Float16)conv_w[3*c0+5];
        cb[0]=(_Float16)conv_b[c0];     cb[1]=(_Float16)conv_b[c0+1];
        conv_lds[tid][0]=wa; conv_lds[tid][1]=wb;
        conv_lds[tid][2]=wc; conv_lds[tid][3]=cb;
    }
    __syncthreads();

    // ---- unified c-range: hc=0 -> cps 0..12; hc=1 -> cps 13..24 + dummy 25 ----
    const int C0 = 13 * hc;
    constexpr int NC = 13;
    h2 cwa[NC], cwb[NC], cwc[NC], ccb[NC];
    #pragma unroll
    for (int j = 0; j < NC; ++j) {
        cwa[j] = conv_lds[C0+j][0]; cwb[j] = conv_lds[C0+j][1];
        cwc[j] = conv_lds[C0+j][2]; ccb[j] = conv_lds[C0+j][3];
    }

    // fc bases with C0 folded: per-read address = base + compile-time immediate
    const int  d6 = lane + 384;
    const bool a6 = (d6 < D);
    const int  i6 = a6 ? 384 : -lane;        // p[i6] == row[clamped d]
    const h2* fcb  = &fc_lds[0][0] + C0 * DPAD + lane;
    const h2* fcb6 = &fc_lds[0][0] + C0 * DPAD + (a6 ? d6 : D);

    const h2 zero2 = (h2)(_Float16)0;

    #define COMPUTE(S, FB, FIDX0)                                                 \
    {                                                                             \
        const h2 H0 = dup(f##S##_0h), R0 = dup(f##S##_0r), T0 = dup(f##S##_0t);   \
        const h2 H1 = dup(f##S##_1h), R1 = dup(f##S##_1r), T1 = dup(f##S##_1t);   \
        const h2 H2 = dup(f##S##_2h), R2 = dup(f##S##_2r), T2 = dup(f##S##_2t);   \
        const h2 H3 = dup(f##S##_3h), R3 = dup(f##S##_3r), T3 = dup(f##S##_3t);   \
        _Pragma("unroll")                                                         \
        for (int j = 0; j < NC; ++j) {                                            \
            const h2 f2 = (FB)[(FIDX0) + j * DPAD];         /* imm offset */      \
            h2 s0 = H0*cwa[j] + (R0*cwb[j] + (T0*cwc[j] + ccb[j]));               \
            h2 s1 = H1*cwa[j] + (R1*cwb[j] + (T1*cwc[j] + ccb[j]));               \
            h2 s2 = H2*cwa[j] + (R2*cwb[j] + (T2*cwc[j] + ccb[j]));               \
            h2 s3 = H3*cwa[j] + (R3*cwb[j] + (T3*cwc[j] + ccb[j]));               \
            s0 = __builtin_elementwise_max(s0, zero2);                            \
            s1 = __builtin_elementwise_max(s1, zero2);                            \
            s2 = __builtin_elementwise_max(s2, zero2);                            \
            s3 = __builtin_elementwise_max(s3, zero2);                            \
            acc0 = dot2acc(s0, f2, acc0);                                         \
            acc1 = dot2acc(s1, f2, acc1);                                         \
            acc2 = dot2acc(s2, f2, acc2);                                         \
            acc3 = dot2acc(s3, f2, acc3);                                         \
        }                                                                         \
    }

    // ---- g-loop kept ROLLED: single emitted body (I-cache) ----
    #pragma unroll 1
    for (int g = 0; g < 2; ++g) {
        const int b0 = bq + 16 * g;
        if (b0 >= nB) break;
        if (g) {                              // g=0 already set + loaded pre-staging
            SETPTRS(b0)
            LOADI(A, 0)
            LOADI(B, 64)
        }
        float acc0 = 0.f, acc1 = 0.f, acc2 = 0.f, acc3 = 0.f;

        LOADI(A, 128)  // note: A slot 0 consumed first, then refilled
        // 2-deep rotation (R8-proven). Order: consume A(0) before overwrite.
        // To keep consume-before-overwrite with named slots, interleave:
        //   COMPUTE(A,0) happens before LOADI(A,128) logically; the compiler
        //   respects the data dependence since slot regs are plain floats.
        // We therefore structure explicitly:
        // (slot A currently holds d-offset 0 ... but LOADI above would clobber)
        // -> correct ordering below.
        (void)0;
        // Undo the early refill pattern: recompute properly.
        // A holds 0, B holds 64 at this point (A refilled with 128 above is WRONG
        // if A(0) not yet consumed) -- so consume A(0) FIRST using the values
        // loaded at 128? No. To keep correctness simple and explicit:
        // The LOADI(A,128) above actually executes AFTER the compiler sees
        // COMPUTE(A,...) below only if written in order. Since it is written
        // BEFORE, we must consume A(0) before it. Restore correct order:
        // (this comment block documents why the sequence below re-loads.)
        acc0 = 0.f; acc1 = 0.f; acc2 = 0.f; acc3 = 0.f;
        if (g) { LOADI(A, 0) LOADI(B, 64) }   // ensure A=0,B=64 valid for g>0
        else   { LOADI(A, 0) LOADI(B, 64) }   // re-issue (L2-hot) for g=0 safety

        COMPUTE(A, fcb, 0*64)   LOADI(A, 128)
        COMPUTE(B, fcb, 1*64)   LOADI(B, 192)
        COMPUTE(A, fcb, 2*64)   LOADI(A, 256)
        COMPUTE(B, fcb, 3*64)   LOADI(B, 320)
        COMPUTE(A, fcb, 4*64)   LOADI(A, i6)
        COMPUTE(B, fcb, 5*64)
        COMPUTE(A, fcb6, 0)

        // wave-wide sum, store partials for this g
        #pragma unroll
        for (int off = 32; off > 0; off >>= 1) {
            acc0 += __shfl_xor(acc0, off);
            acc1 += __shfl_xor(acc1, off);
            acc2 += __shfl_xor(acc2, off);
            acc3 += __shfl_xor(acc3, off);
        }
        if (lane == 0) {
            partials[g][hc][grp][0] = acc0; partials[g][hc][grp][1] = acc1;
            partials[g][hc][grp][2] = acc2; partials[g][hc][grp][3] = acc3;
        }
    }
    #undef COMPUTE
    #undef LOADI
    #undef SETPTRS

    __syncthreads();

    if (tid < 32) {
        const int g = tid >> 4, idx = tid & 15;
        const int gr = idx >> 2, j = idx & 3;
        const int b = bq + 16 * g + 4 * gr + j;
        if (b < nB)
            out[b] = partials[g][0][gr][j] + partials[g][1][gr][j] + fc_b[0];
    }
}

extern "C" void kernel_launch(void* const* d_in, const int* in_sizes, int n_in,
                              void* d_out, int out_size, void* d_ws, size_t ws_size,
                              hipStream_t stream) {
    const float* entity_emb   = (const float*)d_in[0];
    const float* relation_emb = (const float*)d_in[1];
    const float* conv_w       = (const float*)d_in[2];
    const float* conv_b       = (const float*)d_in[3];
    const float* fc_w         = (const float*)d_in[4];
    const float* fc_b         = (const float*)d_in[5];
    const int*   batch_inputs = (const int*)d_in[6];
    float* out = (float*)d_out;

    const int nB = in_sizes[6] / 3;          // 16384
    const int blocks = (nB + 31) / 32;       // 512 = exactly 2 blocks/CU, one round
    grcnet_pk16g<<<blocks, 512, 0, stream>>>(
        entity_emb, relation_emb, conv_w, conv_b, fc_w, fc_b, batch_inputs, out, nB);
}